// Round 10
// baseline (62.005 us; speedup 1.0000x reference)
//
#include <hip/hip_runtime.h>
#include <math.h>

#define INV_2PI_D 0.15915494309189535

// Cross-lane LDS transpose fence. The waitcnt orders the HW; the "memory"
// clobber stops the compiler from reordering the write-pass and read-pass
// (cross-lane dependence is invisible in per-thread SIMT semantics).
#define LDSYNC() asm volatile("s_waitcnt lgkmcnt(0)" ::: "memory")

// pad: a = e + e/16. All transpose phases are <=2-way banked (free, m136).
__device__ __forceinline__ int pad(int e) { return e + (e >> 4); }

__device__ __forceinline__ void bfly(float& ar, float& ai, float& br, float& bi,
                                     float wr, float wi) {
    const float tr = wr * br - wi * bi;
    const float ti = wr * bi + wi * br;
    br = ar - tr; bi = ai - ti;
    ar = ar + tr; ai = ai + ti;
}

// w = exp(2*pi*i * rev): hardware v_sin/v_cos take REVOLUTIONS.
// Twiddle revs are -k/2^m -- exactly representable, no range reduction.
__device__ __forceinline__ void wrev(float rev, float& c, float& s) {
    s = __builtin_amdgcn_sinf(rev);
    c = __builtin_amdgcn_cosf(rev);
}

// Two rows per wave: independent load/butterfly streams give intra-wave ILP
// that covers DS-drain and memory stalls; twiddles, addressing and drains
// are shared across the pair (drains/row 8->4, trans/row 54->27).
__device__ __forceinline__ void fft_rows2(
    const float* __restrict__ xre, const float* __restrict__ xim,
    float* __restrict__ yre, float* __restrict__ yim,
    float* __restrict__ s,              // 2176 floats, private to this wave
    int row0)
{
    const int lane = (int)(threadIdx.x & 63u);

    float re[2][16], im[2][16];

    // ---- bit-reversed loads x2 rows: for fixed r, rev6(lane) permutes one
    // 256B segment -> fully coalesced.
    const int rev6l = (int)(__brev((unsigned)lane) >> 26);
    const int REV4[16] = {0,8,4,12,2,10,6,14,1,9,5,13,3,11,7,15};
#pragma unroll
    for (int p = 0; p < 2; ++p) {
        const size_t bb = (size_t)(row0 + p) << 10;
        const float* xr = xre + bb + rev6l;
        const float* xi = xim + bb + rev6l;
#pragma unroll
        for (int r = 0; r < 16; ++r) {
            re[p][r] = xr[REV4[r] << 6];
            im[p][r] = xi[REV4[r] << 6];
        }
    }

    const int lo = lane & 15;
    const int hi = (lane >> 4) << 8;
    const float lof = (float)lo;

    // ---- L1 stages s=1,2,4,8 (reg-local), exact constant twiddles
    const float W8R[8] = {1.f, 0.9238795325112867f, 0.7071067811865476f,
                          0.3826834323650898f, 0.f, -0.3826834323650898f,
                          -0.7071067811865476f, -0.9238795325112867f};
    const float W8I[8] = {0.f, -0.3826834323650898f, -0.7071067811865476f,
                          -0.9238795325112867f, -1.f, -0.9238795325112867f,
                          -0.7071067811865476f, -0.3826834323650898f};
#pragma unroll
    for (int st = 0; st < 4; ++st) {
        const int S = 1 << st;
#pragma unroll
        for (int p = 0; p < 2; ++p)
#pragma unroll
        for (int rl = 0; rl < 16; ++rl) {
            if (rl & S) continue;
            const int k8 = (rl & (S - 1)) * (8 >> st);
            bfly(re[p][rl], im[p][rl], re[p][rl | S], im[p][rl | S], W8R[k8], W8I[k8]);
        }
    }

    // ---- T1: L1 (e=lane*16+r) -> L3 (e=(lane>>4)*256+r*16+(lane&15))
    // split re/im passes; both rows batched per pass -> one drain serves 32 ops
#pragma unroll
    for (int p = 0; p < 2; ++p)
#pragma unroll
    for (int r = 0; r < 16; ++r) s[p*1088 + pad(lane * 16 + r)] = re[p][r];
    LDSYNC();
#pragma unroll
    for (int p = 0; p < 2; ++p)
#pragma unroll
    for (int r = 0; r < 16; ++r) re[p][r] = s[p*1088 + pad(hi + (r << 4) + lo)];
    LDSYNC();
#pragma unroll
    for (int p = 0; p < 2; ++p)
#pragma unroll
    for (int r = 0; r < 16; ++r) s[p*1088 + pad(lane * 16 + r)] = im[p][r];
    LDSYNC();
#pragma unroll
    for (int p = 0; p < 2; ++p)
#pragma unroll
    for (int r = 0; r < 16; ++r) im[p][r] = s[p*1088 + pad(hi + (r << 4) + lo)];
    LDSYNC();

    // ---- L3 stages s=16,32,64,128; twiddles JIT per stage (caps liveness),
    // shared by both rows.
    {
        float c1, s1;                  // s=16: k = lo
        wrev(-lof * (1.0f / 32.0f), c1, s1);
#pragma unroll
        for (int p = 0; p < 2; ++p)
#pragma unroll
        for (int rl = 0; rl < 16; ++rl) if (!(rl & 1))
            bfly(re[p][rl], im[p][rl], re[p][rl|1], im[p][rl|1], c1, s1);
    }
    {
        float c2[2], s2[2];            // s=32: k = 16m + lo
#pragma unroll
        for (int m = 0; m < 2; ++m)
            wrev(-(16.0f * (float)m + lof) * (1.0f / 64.0f), c2[m], s2[m]);
#pragma unroll
        for (int p = 0; p < 2; ++p)
#pragma unroll
        for (int rl = 0; rl < 16; ++rl) if (!(rl & 2))
            bfly(re[p][rl], im[p][rl], re[p][rl|2], im[p][rl|2], c2[rl & 1], s2[rl & 1]);
    }
    {
        float c4[4], s4[4];            // s=64
#pragma unroll
        for (int m = 0; m < 4; ++m)
            wrev(-(16.0f * (float)m + lof) * (1.0f / 128.0f), c4[m], s4[m]);
#pragma unroll
        for (int p = 0; p < 2; ++p)
#pragma unroll
        for (int rl = 0; rl < 16; ++rl) if (!(rl & 4))
            bfly(re[p][rl], im[p][rl], re[p][rl|4], im[p][rl|4], c4[rl & 3], s4[rl & 3]);
    }
    {
        float c8[8], s8[8];            // s=128
#pragma unroll
        for (int m = 0; m < 8; ++m)
            wrev(-(16.0f * (float)m + lof) * (1.0f / 256.0f), c8[m], s8[m]);
#pragma unroll
        for (int p = 0; p < 2; ++p)
#pragma unroll
        for (int rl = 0; rl < 16; ++rl) if (!(rl & 8))
            bfly(re[p][rl], im[p][rl], re[p][rl|8], im[p][rl|8], c8[rl & 7], s8[rl & 7]);
    }

    // ---- L2-stage twiddles (shared), generated before T2 to overlap DS waits
    const float lf = (float)lane;
    float cz8[8], sz8[8];              // s=512: k = 64m + lane
#pragma unroll
    for (int m = 0; m < 8; ++m)
        wrev(-(64.0f * (float)m + lf) * (1.0f / 1024.0f), cz8[m], sz8[m]);
    float cz4[4], sz4[4];              // s=256
#pragma unroll
    for (int m = 0; m < 4; ++m)
        wrev(-(64.0f * (float)m + lf) * (1.0f / 512.0f), cz4[m], sz4[m]);

    // ---- T2: L3 -> L2 (e=r*64+lane), split passes, rows batched
#pragma unroll
    for (int p = 0; p < 2; ++p)
#pragma unroll
    for (int r = 0; r < 16; ++r) s[p*1088 + pad(hi + (r << 4) + lo)] = re[p][r];
    LDSYNC();
#pragma unroll
    for (int p = 0; p < 2; ++p)
#pragma unroll
    for (int r = 0; r < 16; ++r) re[p][r] = s[p*1088 + pad((r << 6) + lane)];
    LDSYNC();
#pragma unroll
    for (int p = 0; p < 2; ++p)
#pragma unroll
    for (int r = 0; r < 16; ++r) s[p*1088 + pad(hi + (r << 4) + lo)] = im[p][r];
    LDSYNC();
#pragma unroll
    for (int p = 0; p < 2; ++p)
#pragma unroll
    for (int r = 0; r < 16; ++r) im[p][r] = s[p*1088 + pad((r << 6) + lane)];
    LDSYNC();

    // ---- L2 stages s=256,512
#pragma unroll
    for (int p = 0; p < 2; ++p)
#pragma unroll
    for (int rl = 0; rl < 16; ++rl) if (!(rl & 4))
        bfly(re[p][rl], im[p][rl], re[p][rl|4], im[p][rl|4], cz4[rl & 3], sz4[rl & 3]);
#pragma unroll
    for (int p = 0; p < 2; ++p)
#pragma unroll
    for (int rl = 0; rl < 16; ++rl) if (!(rl & 8))
        bfly(re[p][rl], im[p][rl], re[p][rl|8], im[p][rl|8], cz8[rl & 7], sz8[rl & 7]);

    // ---- coalesced stores x2 rows
#pragma unroll
    for (int p = 0; p < 2; ++p) {
        const size_t bb = (size_t)(row0 + p) << 10;
        float* yr = yre + bb + lane;
        float* yi = yim + bb + lane;
#pragma unroll
        for (int r = 0; r < 16; ++r) {
            yr[r << 6] = re[p][r];
            yi[r << 6] = im[p][r];
        }
    }
}

// one-time table: correctly-rounded fl32(log n) and fl32(1/sqrt n), n=1..1024
__global__ __launch_bounds__(256) void table_kernel(float* __restrict__ ws) {
    const int i = (int)(blockIdx.x * 256 + threadIdx.x);
    if (i < 1024) {
        const double nd = (double)(i + 1);
        ws[i]        = (float)log(nd);
        ws[1024 + i] = (float)(1.0 / sqrt(nd));
    }
}

__device__ void z_eval(const float* __restrict__ tin, float* __restrict__ zout,
                       const float* __restrict__ ws, int zblock, int n,
                       float* __restrict__ buf)
{
    // copy 2048-float table ws -> LDS (float4, coalesced)
    for (int i = (int)threadIdx.x; i < 512; i += 256)
        reinterpret_cast<float4*>(buf)[i] = reinterpret_cast<const float4*>(ws)[i];
    __syncthreads();
    const float* slog = buf;
    const float* srsq = buf + 1024;

    const int gid = zblock * 256 + (int)threadIdx.x;
    if (gid >= n) return;

    const float t  = tin[gid];
    const float th = __fmul_rn(t, 0.5f);
    const float logt = (float)log((double)t);
    float theta = __fsub_rn(__fsub_rn(__fmul_rn(th, __fsub_rn(logt, 1.8378770664093453f)), th),
                            0.39269908169872414f);
    theta = __fadd_rn(theta, __fdiv_rn(1.0f, __fmul_rn(48.0f, t)));

    int nt = (int)sqrtf(__fdiv_rn(t, 6.283185307179586f));
    nt = min(max(nt, 10), 1024);

    float acc = 0.0f;
    for (int i = 0; i < nt; ++i) {
        const float p = __fsub_rn(__fmul_rn(t, slog[i]), theta);
        const double rev = (double)p * INV_2PI_D;
        const double fr  = rev - rint(rev);            // |fr| <= 0.5 revolutions
        const float  c   = __builtin_amdgcn_cosf((float)fr);
        acc = __fmaf_rn(srsq[i], c, acc);
    }
    zout[gid] = __fmul_rn(2.0f, acc);
}

__global__ __launch_bounds__(256, 4) void fused_kernel(
    const float* __restrict__ xre, const float* __restrict__ xim,
    const float* __restrict__ tin, const float* __restrict__ ws,
    float* __restrict__ yre, float* __restrict__ yim, float* __restrict__ zout,
    int z_blocks, int nrows, int nz)
{
    __shared__ float s[4][2176];     // 34816 B/block -> 4 blocks/CU, VGPR cap 128

    const int b = (int)blockIdx.x;
    if (b < z_blocks) {
        z_eval(tin, zout, ws, b, nz, &s[0][0]);
    } else {
        const int wid = (int)(threadIdx.x >> 6);
        const int row0 = ((b - z_blocks) << 3) + (wid << 1);
        if (row0 < nrows)
            fft_rows2(xre, xim, yre, yim, s[wid], row0);
    }
}

extern "C" void kernel_launch(void* const* d_in, const int* in_sizes, int n_in,
                              void* d_out, int out_size, void* d_ws, size_t ws_size,
                              hipStream_t stream)
{
    const float* xre = (const float*)d_in[0];
    const float* xim = (const float*)d_in[1];
    const float* t   = (const float*)d_in[2];

    const size_t nfft = (size_t)in_sizes[0];          // 16384*1024
    const int nrows = (int)(nfft >> 10);              // 16384
    const int nz    = in_sizes[2];                    // 262144

    float* yre = (float*)d_out;
    float* yim = yre + nfft;
    float* z   = yre + 2 * nfft;
    float* ws  = (float*)d_ws;                        // 2048 floats of table

    table_kernel<<<4, 256, 0, stream>>>(ws);

    const int f_blocks = (nrows + 7) >> 3;            // 8 rows per block
    const int z_blocks = (nz + 255) >> 8;
    fused_kernel<<<z_blocks + f_blocks, 256, 0, stream>>>(
        xre, xim, t, ws, yre, yim, z, z_blocks, nrows, nz);
}

// Round 11
// 58.638 us; speedup vs baseline: 1.0574x; 1.0574x over previous
//
#include <hip/hip_runtime.h>
#include <math.h>

#define INV_2PI_D 0.15915494309189535

// w = exp(2*pi*i*rev): hardware v_sin/v_cos take REVOLUTIONS.
// Twiddle revs are -k/2^m -- exactly representable, no range reduction.
__device__ __forceinline__ void wrev(float rev, float& c, float& s) {
    s = __builtin_amdgcn_sinf(rev);
    c = __builtin_amdgcn_cosf(rev);
}

// Cross-lane exchange lane <-> lane^S. Dependency is explicit SSA (return
// value), so no compiler-invisible memory hazard and no drains needed.
// S=1,2: DPP quad_perm (VALU). S=8: DPP row_ror:8 == xor8 within row-16
// (VALU). S=4,16: ds_swizzle BitMode xor. S=32: shfl across halves.
template<int S>
__device__ __forceinline__ float xshfl(float x) {
    if constexpr (S == 1)
        return __int_as_float(__builtin_amdgcn_mov_dpp(__float_as_int(x), 0xB1, 0xF, 0xF, true));
    else if constexpr (S == 2)
        return __int_as_float(__builtin_amdgcn_mov_dpp(__float_as_int(x), 0x4E, 0xF, 0xF, true));
    else if constexpr (S == 8)
        return __int_as_float(__builtin_amdgcn_mov_dpp(__float_as_int(x), 0x128, 0xF, 0xF, true));
    else if constexpr (S == 4)
        return __int_as_float(__builtin_amdgcn_ds_swizzle(__float_as_int(x), 0x101F));
    else if constexpr (S == 16)
        return __int_as_float(__builtin_amdgcn_ds_swizzle(__float_as_int(x), 0x401F));
    else
        return __shfl_xor(x, 32, 64);
}

// Cross-lane stage S (element e = r*64 + lane; partner differs in lane bit).
// Pair (e, e+S): u'=u+w*l, l'=u-w*l, k = lane&(S-1) (same for both partners),
// w = exp(-2pi*i*k/(2S)). Lane-selected coeffs: out = c1*own + c2*partner
// with upper (lane&S==0): c1=(1,0), c2=w ; lower: c1=-w, c2=(1,0).
template<int S>
__device__ __forceinline__ void stage_x(float (&re)[16], float (&im)[16], int lane) {
    float wr, wi;
    wrev(-(float)(lane & (S - 1)) * (0.5f / (float)S), wr, wi);
    const bool up = (lane & S) == 0;
    const float c1r = up ? 1.0f : -wr;
    const float c1i = up ? 0.0f : -wi;
    const float c2r = up ? wr : 1.0f;
    const float c2i = up ? wi : 0.0f;
#pragma unroll
    for (int r = 0; r < 16; ++r) {
        const float pr = xshfl<S>(re[r]);
        const float pi = xshfl<S>(im[r]);
        const float a = re[r], b = im[r];
        re[r] = a * c1r - b * c1i + pr * c2r - pi * c2i;
        im[r] = a * c1i + b * c1r + pr * c2i + pi * c2r;
    }
}

// S=1: w=(1,0) for all lanes -> out = partner + sgn*own, 2 fma/element.
__device__ __forceinline__ void stage_x1(float (&re)[16], float (&im)[16], int lane) {
    const float sgn = (lane & 1) ? -1.0f : 1.0f;
#pragma unroll
    for (int r = 0; r < 16; ++r) {
        const float pr = xshfl<1>(re[r]);
        const float pi = xshfl<1>(im[r]);
        re[r] = __fmaf_rn(sgn, re[r], pr);
        im[r] = __fmaf_rn(sgn, im[r], pi);
    }
}

__device__ __forceinline__ void bfly(float& ar, float& ai, float& br, float& bi,
                                     float wr, float wi) {
    const float tr = wr * br - wi * bi;
    const float ti = wr * bi + wi * br;
    br = ar - tr; bi = ai - ti;
    ar = ar + tr; ai = ai + ti;
}

// Register-local stage, span S = 64*M: pairs (r, r|M), k = 64*(r&(M-1))+lane,
// w = exp(-2pi*i*k/(128M)).
template<int M>
__device__ __forceinline__ void stage_r(float (&re)[16], float (&im)[16], float lanef) {
    float cw[M], sw[M];
#pragma unroll
    for (int m = 0; m < M; ++m)
        wrev(-(64.0f * (float)m + lanef) * (1.0f / (128.0f * (float)M)), cw[m], sw[m]);
#pragma unroll
    for (int rl = 0; rl < 16; ++rl) {
        if (rl & M) continue;
        bfly(re[rl], im[rl], re[rl | M], im[rl | M], cw[rl & (M - 1)], sw[rl & (M - 1)]);
    }
}

// One 1024-pt FFT per wave, zero LDS, zero barriers/drains.
// Element map: e = r*64 + lane (fixed). Bit-reversed load folded into
// float4 gather: float-offset rev6(lane)*16 + 4q + j holds element with
// rev4(r) = 4q+j, i.e. r = REV4[4q+j]. 1KB contiguous per instruction.
__device__ __forceinline__ void fft_row(
    const float* __restrict__ xre, const float* __restrict__ xim,
    float* __restrict__ yre, float* __restrict__ yim, int row)
{
    const int lane = (int)(threadIdx.x & 63u);
    const size_t base = (size_t)row << 10;

    float re[16], im[16];

    const int rev6l = (int)(__brev((unsigned)lane) >> 26);
    const float4* xr4 = reinterpret_cast<const float4*>(xre + base) + (rev6l << 2);
    const float4* xi4 = reinterpret_cast<const float4*>(xim + base) + (rev6l << 2);

    static constexpr int RM[4][4] = {
        {0, 8, 4, 12}, {2, 10, 6, 14}, {1, 9, 5, 13}, {3, 11, 7, 15}};
#pragma unroll
    for (int q = 0; q < 4; ++q) {
        const float4 vr = xr4[q];
        const float4 vi = xi4[q];
        re[RM[q][0]] = vr.x; re[RM[q][1]] = vr.y; re[RM[q][2]] = vr.z; re[RM[q][3]] = vr.w;
        im[RM[q][0]] = vi.x; im[RM[q][1]] = vi.y; im[RM[q][2]] = vi.z; im[RM[q][3]] = vi.w;
    }

    // lane-bit stages
    stage_x1(re, im, lane);
    stage_x<2>(re, im, lane);
    stage_x<4>(re, im, lane);
    stage_x<8>(re, im, lane);
    stage_x<16>(re, im, lane);
    stage_x<32>(re, im, lane);

    // register-bit stages (S = 64,128,256,512)
    const float lanef = (float)lane;
    stage_r<1>(re, im, lanef);
    stage_r<2>(re, im, lanef);
    stage_r<4>(re, im, lanef);
    stage_r<8>(re, im, lanef);

    // coalesced stores: element e = r*64 + lane
    float* yr = yre + base + lane;
    float* yi = yim + base + lane;
#pragma unroll
    for (int r = 0; r < 16; ++r) {
        yr[r << 6] = re[r];
        yi[r << 6] = im[r];
    }
}

// one-time table: correctly-rounded fl32(log n) and fl32(1/sqrt n), n=1..1024
__global__ __launch_bounds__(256) void table_kernel(float* __restrict__ ws) {
    const int i = (int)(blockIdx.x * 256 + threadIdx.x);
    if (i < 1024) {
        const double nd = (double)(i + 1);
        ws[i]        = (float)log(nd);
        ws[1024 + i] = (float)(1.0 / sqrt(nd));
    }
}

__device__ void z_eval(const float* __restrict__ tin, float* __restrict__ zout,
                       const float* __restrict__ ws, int zblock, int n,
                       float* __restrict__ buf)
{
    // copy 2048-float table ws -> LDS (float4, coalesced)
    for (int i = (int)threadIdx.x; i < 512; i += 256)
        reinterpret_cast<float4*>(buf)[i] = reinterpret_cast<const float4*>(ws)[i];
    __syncthreads();
    const float* slog = buf;
    const float* srsq = buf + 1024;

    const int gid = zblock * 256 + (int)threadIdx.x;
    if (gid >= n) return;

    const float t  = tin[gid];
    const float th = __fmul_rn(t, 0.5f);
    const float logt = (float)log((double)t);
    float theta = __fsub_rn(__fsub_rn(__fmul_rn(th, __fsub_rn(logt, 1.8378770664093453f)), th),
                            0.39269908169872414f);
    theta = __fadd_rn(theta, __fdiv_rn(1.0f, __fmul_rn(48.0f, t)));

    int nt = (int)sqrtf(__fdiv_rn(t, 6.283185307179586f));
    nt = min(max(nt, 10), 1024);

    float acc = 0.0f;
    for (int i = 0; i < nt; ++i) {
        const float p = __fsub_rn(__fmul_rn(t, slog[i]), theta);
        const double rev = (double)p * INV_2PI_D;
        const double fr  = rev - rint(rev);            // |fr| <= 0.5 revolutions
        const float  c   = __builtin_amdgcn_cosf((float)fr);
        acc = __fmaf_rn(srsq[i], c, acc);
    }
    zout[gid] = __fmul_rn(2.0f, acc);
}

__global__ __launch_bounds__(256, 4) void fused_kernel(
    const float* __restrict__ xre, const float* __restrict__ xim,
    const float* __restrict__ tin, const float* __restrict__ ws,
    float* __restrict__ yre, float* __restrict__ yim, float* __restrict__ zout,
    int z_blocks, int nrows, int nz)
{
    __shared__ float zbuf[2048];     // 8 KB: Z table only; FFT uses no LDS

    const int b = (int)blockIdx.x;
    if (b < z_blocks) {
        z_eval(tin, zout, ws, b, nz, zbuf);
    } else {
        const int wid = (int)(threadIdx.x >> 6);
        const int row = ((b - z_blocks) << 2) | wid;
        if (row < nrows)
            fft_row(xre, xim, yre, yim, row);
    }
}

extern "C" void kernel_launch(void* const* d_in, const int* in_sizes, int n_in,
                              void* d_out, int out_size, void* d_ws, size_t ws_size,
                              hipStream_t stream)
{
    const float* xre = (const float*)d_in[0];
    const float* xim = (const float*)d_in[1];
    const float* t   = (const float*)d_in[2];

    const size_t nfft = (size_t)in_sizes[0];          // 16384*1024
    const int nrows = (int)(nfft >> 10);              // 16384
    const int nz    = in_sizes[2];                    // 262144

    float* yre = (float*)d_out;
    float* yim = yre + nfft;
    float* z   = yre + 2 * nfft;
    float* ws  = (float*)d_ws;                        // 2048 floats of table

    table_kernel<<<4, 256, 0, stream>>>(ws);

    const int f_blocks = (nrows + 3) >> 2;            // 4 rows per block
    const int z_blocks = (nz + 255) >> 8;
    fused_kernel<<<z_blocks + f_blocks, 256, 0, stream>>>(
        xre, xim, t, ws, yre, yim, z, z_blocks, nrows, nz);
}